// Round 6
// baseline (201.643 us; speedup 1.0000x reference)
//
#include <hip/hip_runtime.h>
#include <hip/hip_bf16.h>

#define BSZ 4096
#define DIM 512
#define NCLS 64
#define MARGIN_F 1.0f
#define NT 32                      // 128-tiles per dim
#define NBLK (NT * NT)             // full grid, 1024 blocks of 128x128
#define NSL (2 * NT)               // 64-column slices
#define NFIN 16                    // finalize shards (16*256 = 4096 rows)
#define LDP 40                     // padded LDS row stride in u16 (80 B)

typedef short short8 __attribute__((ext_vector_type(8)));
typedef float floatx4 __attribute__((ext_vector_type(4)));
typedef unsigned short u16;

// ---------------- workspace layout ----------------
// [0)        : ebf16 BSZ*DIM u16 (4 MiB) normalized bf16 embeddings
// [OFF_PP)   : part_ps [NSL][BSZ] float (1 MiB) row j vs 64-col-tile s
// [OFF_PN)   : part_nm [NSL][BSZ] uint  (1 MiB) (float bits; dist>=0)
// [OFF_ACC)  : float total; int nv; int counter; int counter2
#define OFF_PP  (BSZ * DIM * 2)
#define OFF_PN  (OFF_PP + NSL * BSZ * 4)
#define OFF_ACC (OFF_PN + NSL * BSZ * 4)

__device__ __forceinline__ u16 f2bf_rne(float f) {
    unsigned x = __float_as_uint(f);
    x += 0x7FFFu + ((x >> 16) & 1u);
    return (u16)(x >> 16);
}

// 4 waves/block, one row/wave: L2-normalize, cast bf16; init accumulators.
// (partials need NO init: every slot is written exactly once by the gemm)
__global__ __launch_bounds__(256) void ht_normalize(
        const float* __restrict__ emb, u16* __restrict__ ebf,
        float* __restrict__ acc_total, int* __restrict__ acc_nv,
        int* __restrict__ counter, int* __restrict__ counter2) {
    const int lane = threadIdx.x & 63;
    const int row = blockIdx.x * 4 + (threadIdx.x >> 6);
    const float4* r4 = (const float4*)(emb + (size_t)row * DIM);
    float4 v0 = r4[lane * 2];
    float4 v1 = r4[lane * 2 + 1];
    float s = v0.x * v0.x + v0.y * v0.y + v0.z * v0.z + v0.w * v0.w
            + v1.x * v1.x + v1.y * v1.y + v1.z * v1.z + v1.w * v1.w;
#pragma unroll
    for (int off = 1; off < 64; off <<= 1) s += __shfl_xor(s, off);
    const float inv = 1.0f / fmaxf(sqrtf(s), 1e-12f);

    uint4 o;
    o.x = (unsigned)f2bf_rne(v0.x * inv) | ((unsigned)f2bf_rne(v0.y * inv) << 16);
    o.y = (unsigned)f2bf_rne(v0.z * inv) | ((unsigned)f2bf_rne(v0.w * inv) << 16);
    o.z = (unsigned)f2bf_rne(v1.x * inv) | ((unsigned)f2bf_rne(v1.y * inv) << 16);
    o.w = (unsigned)f2bf_rne(v1.z * inv) | ((unsigned)f2bf_rne(v1.w * inv) << 16);
    ((uint4*)(ebf + (size_t)row * DIM))[lane] = o;

    if (blockIdx.x == 0 && threadIdx.x == 0) {
        *acc_total = 0.0f; *acc_nv = 0; *counter = 0; *counter2 = 0;
    }
}

// Full 32x32 grid of 128x128 tiles (R1 structure, proven fastest).
// 4 waves 2x2; each wave 64x64 via 4x4 mfma_f32_16x16x32_bf16.
// Register staging (uint4, 64B-coalesced global reads) -> ds_write_b128 into
// PADDED LDS [128][LDP=40 u16]: bank stride 20 dwords -> max 2-way (free),
// vs R1's unpadded 8-way (2.1M conflict cycles).
// Epilogue: part[2*bx+(wc>>6)][gi] has exactly ONE writer -> plain stores,
// no atomics, no init. Last NFIN blocks (completion counter) run finalize.
__global__ __launch_bounds__(256) void ht_gemm_reduce(
        const u16* __restrict__ ebf, const int* __restrict__ labels,
        float* __restrict__ part_ps, unsigned* __restrict__ part_nm,
        float* __restrict__ acc_total, int* __restrict__ acc_nv,
        int* __restrict__ counter, int* __restrict__ counter2,
        float* __restrict__ out) {
    __shared__ u16 sA[128 * LDP];
    __shared__ u16 sB[128 * LDP];
    __shared__ int sLI[128];             // A labels; reused as hist in finalize
    __shared__ int sLJ[128];
    __shared__ float sT[4];
    __shared__ int sN[4];
    __shared__ int sOrd;

    const int t = threadIdx.x;
    const int by = blockIdx.x >> 5;
    const int bx = blockIdx.x & 31;
    const int row0 = by * 128;
    const int col0 = bx * 128;

    if (t < 128) sLI[t] = labels[row0 + t];
    else         sLJ[t - 128] = labels[col0 + t - 128];

    const int lane = t & 63;
    const int wave = t >> 6;
    const int wr = (wave >> 1) * 64;
    const int wc = (wave & 1) * 64;
    const int l15 = lane & 15;
    const int quad = lane >> 4;

    // staging map (R1): seg lin -> row lin>>2, 16B-granule lin&3
    const int lin0 = t, lin1 = 256 + t;
    const int ar0 = lin0 >> 2, g0 = lin0 & 3;
    const int ar1 = lin1 >> 2, g1 = lin1 & 3;

    floatx4 acc[4][4] = {};

    for (int kk = 0; kk < DIM; kk += 32) {
        uint4 a0 = *(const uint4*)(ebf + (size_t)(row0 + ar0) * DIM + kk + g0 * 8);
        uint4 a1 = *(const uint4*)(ebf + (size_t)(row0 + ar1) * DIM + kk + g1 * 8);
        uint4 b0 = *(const uint4*)(ebf + (size_t)(col0 + ar0) * DIM + kk + g0 * 8);
        uint4 b1 = *(const uint4*)(ebf + (size_t)(col0 + ar1) * DIM + kk + g1 * 8);
        __syncthreads();
        *(uint4*)(sA + ar0 * LDP + g0 * 8) = a0;
        *(uint4*)(sA + ar1 * LDP + g1 * 8) = a1;
        *(uint4*)(sB + ar0 * LDP + g0 * 8) = b0;
        *(uint4*)(sB + ar1 * LDP + g1 * 8) = b1;
        __syncthreads();

        short8 af[4], bf[4];
#pragma unroll
        for (int mi = 0; mi < 4; ++mi)
            af[mi] = *(const short8*)(sA + (wr + mi * 16 + l15) * LDP + quad * 8);
#pragma unroll
        for (int ni = 0; ni < 4; ++ni)
            bf[ni] = *(const short8*)(sB + (wc + ni * 16 + l15) * LDP + quad * 8);
#pragma unroll
        for (int mi = 0; mi < 4; ++mi)
#pragma unroll
            for (int ni = 0; ni < 4; ++ni)
                acc[mi][ni] = __builtin_amdgcn_mfma_f32_16x16x32_bf16(
                    af[mi], bf[ni], acc[mi][ni], 0, 0, 0);
    }

    // epilogue: C/D layout col=l15, row=quad*4+reg (m89/m91 verified)
    const float INF = __uint_as_float(0x7F800000u);
    const int rslice = 2 * bx + (wc >> 6);
#pragma unroll
    for (int mi = 0; mi < 4; ++mi) {
        const int rbase = wr + mi * 16 + quad * 4;
#pragma unroll
        for (int r = 0; r < 4; ++r) {
            const int rloc = rbase + r;
            const int gi = row0 + rloc;
            const int rl = sLI[rloc];
            float ps = 0.0f, nm = INF;
#pragma unroll
            for (int ni = 0; ni < 4; ++ni) {
                const int cloc = wc + ni * 16 + l15;
                const int gj = col0 + cloc;
                const int cl = sLJ[cloc];
                const float d = sqrtf(fmaxf(2.0f - 2.0f * acc[mi][ni][r], 0.0f));
                if (rl == cl) { if (gi != gj) ps += d; }
                else          { nm = fminf(nm, d); }
            }
#pragma unroll
            for (int off = 1; off < 16; off <<= 1) {
                ps += __shfl_xor(ps, off);
                nm = fminf(nm, __shfl_xor(nm, off));
            }
            if (l15 == 0) {                 // sole writer of (rslice, gi)
                part_ps[rslice * BSZ + gi] = ps;
                part_nm[rslice * BSZ + gi] = __float_as_uint(nm);
            }
        }
    }

    // ---- fused finalize: last NFIN blocks shard the row reduction ----
    __syncthreads();
    __threadfence();                       // publish partials device-wide
    if (t == 0)
        sOrd = __hip_atomic_fetch_add(counter, 1, __ATOMIC_ACQ_REL,
                                      __HIP_MEMORY_SCOPE_AGENT);
    __syncthreads();
    const int myord = sOrd;
    if (myord < NBLK - NFIN) return;
    // spin-safe: myord >= NBLK-NFIN implies all NBLK blocks were dispatched
    // and >= NBLK-NFIN non-spinners have freed their CU slots.
    if (t == 0) {
        while (__hip_atomic_load(counter, __ATOMIC_ACQUIRE,
                                 __HIP_MEMORY_SCOPE_AGENT) < NBLK)
            __builtin_amdgcn_s_sleep(2);
    }
    __syncthreads();

    if (t < NCLS) sLI[t] = 0;              // reuse sLI as class histogram
    __syncthreads();
    for (int i = t; i < BSZ; i += 256) atomicAdd(&sLI[labels[i]], 1);
    __syncthreads();

    const int shard = myord - (NBLK - NFIN);
    const int j = shard * 256 + t;         // one row per thread, coalesced
    float ps = 0.0f, nm = INF;
#pragma unroll 8
    for (int s = 0; s < NSL; ++s) {
        ps += part_ps[s * BSZ + j];
        nm = fminf(nm, __uint_as_float(part_nm[s * BSZ + j]));
    }
    const int cnt = sLI[labels[j]];
    const int pc = cnt - 1;
    const int nc = BSZ - cnt;
    float loss = 0.0f;
    int lv = 0;
    if (pc > 0 && nc > 0) {
        loss = fmaxf(ps / (float)pc - nm + MARGIN_F, 0.0f);
        lv = 1;
    }
#pragma unroll
    for (int off = 1; off < 64; off <<= 1) {
        loss += __shfl_xor(loss, off);
        lv += __shfl_xor(lv, off);
    }
    if ((t & 63) == 0) { sT[t >> 6] = loss; sN[t >> 6] = lv; }
    __syncthreads();
    if (t == 0) {
        const float tt = sT[0] + sT[1] + sT[2] + sT[3];
        const int nn = sN[0] + sN[1] + sN[2] + sN[3];
        __hip_atomic_fetch_add(acc_total, tt, __ATOMIC_ACQ_REL,
                               __HIP_MEMORY_SCOPE_AGENT);
        __hip_atomic_fetch_add(acc_nv, nn, __ATOMIC_ACQ_REL,
                               __HIP_MEMORY_SCOPE_AGENT);
        const int old2 = __hip_atomic_fetch_add(counter2, 1, __ATOMIC_ACQ_REL,
                                                __HIP_MEMORY_SCOPE_AGENT);
        if (old2 == NFIN - 1) {
            const float ft = __hip_atomic_load(acc_total, __ATOMIC_ACQUIRE,
                                               __HIP_MEMORY_SCOPE_AGENT);
            const int fn = __hip_atomic_load(acc_nv, __ATOMIC_ACQUIRE,
                                             __HIP_MEMORY_SCOPE_AGENT);
            out[0] = (fn > 0) ? ft / (float)fn : 0.0f;
        }
    }
}

extern "C" void kernel_launch(void* const* d_in, const int* in_sizes, int n_in,
                              void* d_out, int out_size, void* d_ws, size_t ws_size,
                              hipStream_t stream) {
    const float* emb = (const float*)d_in[0];
    const int* labels = (const int*)d_in[1];
    float* out = (float*)d_out;
    char* ws = (char*)d_ws;

    u16* ebf = (u16*)ws;
    float* part_ps = (float*)(ws + OFF_PP);
    unsigned* part_nm = (unsigned*)(ws + OFF_PN);
    float* acc_total = (float*)(ws + OFF_ACC);
    int* acc_nv = (int*)(ws + OFF_ACC + 4);
    int* counter = (int*)(ws + OFF_ACC + 8);
    int* counter2 = (int*)(ws + OFF_ACC + 12);

    ht_normalize<<<BSZ / 4, 256, 0, stream>>>(emb, ebf, acc_total, acc_nv,
                                              counter, counter2);
    ht_gemm_reduce<<<NBLK, 256, 0, stream>>>(ebf, labels, part_ps, part_nm,
                                             acc_total, acc_nv, counter,
                                             counter2, out);
}

// Round 7
// 108.783 us; speedup vs baseline: 1.8536x; 1.8536x over previous
//
#include <hip/hip_runtime.h>
#include <hip/hip_bf16.h>

#define BSZ 4096
#define DIM 512
#define NCLS 64
#define MARGIN_F 1.0f
#define NT 32                      // 128-tiles per dim
#define NBLK (NT * NT)             // 1024 blocks of 128x128
#define NSL (2 * NT)               // 64-column slices
#define NFIN 16                    // finalize blocks (16*256 = 4096 rows)

typedef short short8 __attribute__((ext_vector_type(8)));
typedef float floatx4 __attribute__((ext_vector_type(4)));
typedef unsigned short u16;

// ---------------- workspace layout ----------------
// [0)        : ebf16 BSZ*DIM u16 (4 MiB) normalized bf16 embeddings
// [OFF_PP)   : part_ps [NSL][BSZ] float (1 MiB) row j vs 64-col-tile s
// [OFF_PN)   : part_nm [NSL][BSZ] uint  (1 MiB) (float bits; dist>=0)
// [OFF_ACC)  : float total; int nv; int counter2
#define OFF_PP  (BSZ * DIM * 2)
#define OFF_PN  (OFF_PP + NSL * BSZ * 4)
#define OFF_ACC (OFF_PN + NSL * BSZ * 4)

__device__ __forceinline__ u16 f2bf_rne(float f) {
    unsigned x = __float_as_uint(f);
    x += 0x7FFFu + ((x >> 16) & 1u);
    return (u16)(x >> 16);
}

// async global->LDS, 16 B/lane; LDS dest = wave-uniform base + lane*16
__device__ __forceinline__ void gld_lds16(const u16* g, u16* l) {
    __builtin_amdgcn_global_load_lds(
        (const __attribute__((address_space(1))) unsigned int*)g,
        (__attribute__((address_space(3))) unsigned int*)l, 16, 0, 0);
}

// 4 waves/block, one row/wave: L2-normalize, cast bf16; init scalar accums.
__global__ __launch_bounds__(256) void ht_normalize(
        const float* __restrict__ emb, u16* __restrict__ ebf,
        float* __restrict__ acc_total, int* __restrict__ acc_nv,
        int* __restrict__ counter2) {
    const int lane = threadIdx.x & 63;
    const int row = blockIdx.x * 4 + (threadIdx.x >> 6);
    const float4* r4 = (const float4*)(emb + (size_t)row * DIM);
    float4 v0 = r4[lane * 2];
    float4 v1 = r4[lane * 2 + 1];
    float s = v0.x * v0.x + v0.y * v0.y + v0.z * v0.z + v0.w * v0.w
            + v1.x * v1.x + v1.y * v1.y + v1.z * v1.z + v1.w * v1.w;
#pragma unroll
    for (int off = 1; off < 64; off <<= 1) s += __shfl_xor(s, off);
    const float inv = 1.0f / fmaxf(sqrtf(s), 1e-12f);

    uint4 o;
    o.x = (unsigned)f2bf_rne(v0.x * inv) | ((unsigned)f2bf_rne(v0.y * inv) << 16);
    o.y = (unsigned)f2bf_rne(v0.z * inv) | ((unsigned)f2bf_rne(v0.w * inv) << 16);
    o.z = (unsigned)f2bf_rne(v1.x * inv) | ((unsigned)f2bf_rne(v1.y * inv) << 16);
    o.w = (unsigned)f2bf_rne(v1.z * inv) | ((unsigned)f2bf_rne(v1.w * inv) << 16);
    ((uint4*)(ebf + (size_t)row * DIM))[lane] = o;

    if (blockIdx.x == 0 && threadIdx.x == 0) {
        *acc_total = 0.0f; *acc_nv = 0; *counter2 = 0;
    }
}

// 128x128 tile per block (R1 structure), 4 waves 2x2, each wave 64x64 via
// 4x4 mfma_f32_16x16x32_bf16. Staging via global_load_lds(16B) into
// row-major UNPADDED [128][32] double-buffered LDS: segment s (=lin idx)
// lands at LDS byte s*16 (wave-uniform base + lane*16, m104-compatible) and
// global addr keeps 4 lanes contiguous per 64B row-chunk (m97 coalescing).
// Single barrier per k-step: barrier -> issue gld(k+1) into buf^1 ->
// ds_read+MFMA on buf (prefetch flies behind compute).
// Epilogue: part[2*bx+(wc>>6)][gi] has exactly ONE writer -> plain stores,
// no atomics, no init, no fences (separate finalize kernel gives visibility).
__global__ __launch_bounds__(256) void ht_gemm_reduce(
        const u16* __restrict__ ebf, const int* __restrict__ labels,
        float* __restrict__ part_ps, unsigned* __restrict__ part_nm) {
    __shared__ u16 sA[2][128 * 32];
    __shared__ u16 sB[2][128 * 32];
    __shared__ int sLI[128];
    __shared__ int sLJ[128];

    const int t = threadIdx.x;
    const int by = blockIdx.x >> 5;
    const int bx = blockIdx.x & 31;
    const int row0 = by * 128;
    const int col0 = bx * 128;

    if (t < 128) sLI[t] = labels[row0 + t];
    else         sLJ[t - 128] = labels[col0 + t - 128];

    const int lane = t & 63;
    const int wave = t >> 6;
    const int wr = (wave >> 1) * 64;
    const int wc = (wave & 1) * 64;
    const int l15 = lane & 15;
    const int quad = lane >> 4;

    // segments s0 = t, s1 = 256+t; row = s>>2, granule = s&3 (16B each).
    // global per-lane addr; LDS base wave-uniform (s*8 u16 for lane 0).
    const int s0 = t, s1 = 256 + t;
    const u16* gA0 = ebf + (size_t)(row0 + (s0 >> 2)) * DIM + (s0 & 3) * 8;
    const u16* gA1 = ebf + (size_t)(row0 + (s1 >> 2)) * DIM + (s1 & 3) * 8;
    const u16* gB0 = ebf + (size_t)(col0 + (s0 >> 2)) * DIM + (s0 & 3) * 8;
    const u16* gB1 = ebf + (size_t)(col0 + (s1 >> 2)) * DIM + (s1 & 3) * 8;
    const int lb0 = wave * 64 * 8;          // u16 offset of wave's 1KB chunk
    const int lb1 = (256 + wave * 64) * 8;

    floatx4 acc[4][4] = {};

    // prologue: stage k=0 into buf 0
    gld_lds16(gA0, &sA[0][lb0]);
    gld_lds16(gA1, &sA[0][lb1]);
    gld_lds16(gB0, &sB[0][lb0]);
    gld_lds16(gB1, &sB[0][lb1]);

    int cur = 0;
    for (int ks = 0; ks < DIM / 32; ++ks) {
        __syncthreads();  // vmcnt drained: buf[cur] ready; buf[cur^1] reads done
        if (ks + 1 < DIM / 32) {
            const int kb = (ks + 1) * 32;
            gld_lds16(gA0 + kb, &sA[cur ^ 1][lb0]);
            gld_lds16(gA1 + kb, &sA[cur ^ 1][lb1]);
            gld_lds16(gB0 + kb, &sB[cur ^ 1][lb0]);
            gld_lds16(gB1 + kb, &sB[cur ^ 1][lb1]);
        }
        short8 af[4], bf[4];
#pragma unroll
        for (int mi = 0; mi < 4; ++mi)
            af[mi] = *(const short8*)(&sA[cur][(wr + mi * 16 + l15) * 32 + quad * 8]);
#pragma unroll
        for (int ni = 0; ni < 4; ++ni)
            bf[ni] = *(const short8*)(&sB[cur][(wc + ni * 16 + l15) * 32 + quad * 8]);
#pragma unroll
        for (int mi = 0; mi < 4; ++mi)
#pragma unroll
            for (int ni = 0; ni < 4; ++ni)
                acc[mi][ni] = __builtin_amdgcn_mfma_f32_16x16x32_bf16(
                    af[mi], bf[ni], acc[mi][ni], 0, 0, 0);
        cur ^= 1;
    }

    // epilogue: C/D layout col=l15, row=quad*4+reg (m89/m91 verified)
    const float INF = __uint_as_float(0x7F800000u);
    const int rslice = 2 * bx + (wc >> 6);
#pragma unroll
    for (int mi = 0; mi < 4; ++mi) {
        const int rbase = wr + mi * 16 + quad * 4;
#pragma unroll
        for (int r = 0; r < 4; ++r) {
            const int rloc = rbase + r;
            const int gi = row0 + rloc;
            const int rl = sLI[rloc];
            float ps = 0.0f, nm = INF;
#pragma unroll
            for (int ni = 0; ni < 4; ++ni) {
                const int cloc = wc + ni * 16 + l15;
                const int gj = col0 + cloc;
                const int cl = sLJ[cloc];
                const float d = sqrtf(fmaxf(2.0f - 2.0f * acc[mi][ni][r], 0.0f));
                if (rl == cl) { if (gi != gj) ps += d; }
                else          { nm = fminf(nm, d); }
            }
#pragma unroll
            for (int off = 1; off < 16; off <<= 1) {
                ps += __shfl_xor(ps, off);
                nm = fminf(nm, __shfl_xor(nm, off));
            }
            if (l15 == 0) {                 // sole writer of (rslice, gi)
                part_ps[rslice * BSZ + gi] = ps;
                part_nm[rslice * BSZ + gi] = __float_as_uint(nm);
            }
        }
    }
}

// 16 blocks x 256 threads: one row per thread. Reduce 64 slices (coalesced),
// per-block loss partials -> 2 device atomics per block; last block writes out.
__global__ __launch_bounds__(256) void ht_finalize(
        const float* __restrict__ part_ps, const unsigned* __restrict__ part_nm,
        const int* __restrict__ labels, float* __restrict__ acc_total,
        int* __restrict__ acc_nv, int* __restrict__ counter2,
        float* __restrict__ out) {
    __shared__ int hist[NCLS];
    __shared__ float sT[4];
    __shared__ int sN[4];
    const int t = threadIdx.x;
    if (t < NCLS) hist[t] = 0;
    __syncthreads();
    for (int i = t; i < BSZ; i += 256) atomicAdd(&hist[labels[i]], 1);
    __syncthreads();

    const int j = blockIdx.x * 256 + t;
    float ps = 0.0f;
    float nm = __uint_as_float(0x7F800000u);
#pragma unroll 8
    for (int s = 0; s < NSL; ++s) {
        ps += part_ps[s * BSZ + j];
        nm = fminf(nm, __uint_as_float(part_nm[s * BSZ + j]));
    }
    const int cnt = hist[labels[j]];
    const int pc = cnt - 1;
    const int nc = BSZ - cnt;
    float loss = 0.0f;
    int lv = 0;
    if (pc > 0 && nc > 0) {
        loss = fmaxf(ps / (float)pc - nm + MARGIN_F, 0.0f);
        lv = 1;
    }
#pragma unroll
    for (int off = 1; off < 64; off <<= 1) {
        loss += __shfl_xor(loss, off);
        lv += __shfl_xor(lv, off);
    }
    if ((t & 63) == 0) { sT[t >> 6] = loss; sN[t >> 6] = lv; }
    __syncthreads();
    if (t == 0) {
        const float tt = sT[0] + sT[1] + sT[2] + sT[3];
        const int nn = sN[0] + sN[1] + sN[2] + sN[3];
        __hip_atomic_fetch_add(acc_total, tt, __ATOMIC_ACQ_REL,
                               __HIP_MEMORY_SCOPE_AGENT);
        __hip_atomic_fetch_add(acc_nv, nn, __ATOMIC_ACQ_REL,
                               __HIP_MEMORY_SCOPE_AGENT);
        const int old2 = __hip_atomic_fetch_add(counter2, 1, __ATOMIC_ACQ_REL,
                                                __HIP_MEMORY_SCOPE_AGENT);
        if (old2 == NFIN - 1) {
            const float ft = __hip_atomic_load(acc_total, __ATOMIC_ACQUIRE,
                                               __HIP_MEMORY_SCOPE_AGENT);
            const int fn = __hip_atomic_load(acc_nv, __ATOMIC_ACQUIRE,
                                             __HIP_MEMORY_SCOPE_AGENT);
            out[0] = (fn > 0) ? ft / (float)fn : 0.0f;
        }
    }
}

extern "C" void kernel_launch(void* const* d_in, const int* in_sizes, int n_in,
                              void* d_out, int out_size, void* d_ws, size_t ws_size,
                              hipStream_t stream) {
    const float* emb = (const float*)d_in[0];
    const int* labels = (const int*)d_in[1];
    float* out = (float*)d_out;
    char* ws = (char*)d_ws;

    u16* ebf = (u16*)ws;
    float* part_ps = (float*)(ws + OFF_PP);
    unsigned* part_nm = (unsigned*)(ws + OFF_PN);
    float* acc_total = (float*)(ws + OFF_ACC);
    int* acc_nv = (int*)(ws + OFF_ACC + 4);
    int* counter2 = (int*)(ws + OFF_ACC + 8);

    ht_normalize<<<BSZ / 4, 256, 0, stream>>>(emb, ebf, acc_total, acc_nv,
                                              counter2);
    ht_gemm_reduce<<<NBLK, 256, 0, stream>>>(ebf, labels, part_ps, part_nm);
    ht_finalize<<<NFIN, 256, 0, stream>>>(part_ps, part_nm, labels,
                                          acc_total, acc_nv, counter2, out);
}

// Round 8
// 105.271 us; speedup vs baseline: 1.9155x; 1.0334x over previous
//
#include <hip/hip_runtime.h>
#include <hip/hip_bf16.h>

#define BSZ 4096
#define DIM 512
#define NCLS 64
#define MARGIN_F 1.0f
#define NT 32                      // 128-tiles per dim
#define NBLK (NT * NT)             // 1024 blocks of 128x128
#define NSL (2 * NT)               // 64-column slices
#define NFIN 16                    // finalize blocks (16*256 = 4096 rows)

typedef short short8 __attribute__((ext_vector_type(8)));
typedef float floatx4 __attribute__((ext_vector_type(4)));
typedef unsigned short u16;

// ---------------- workspace layout ----------------
// [0)        : ebf16 BSZ*DIM u16 (4 MiB) normalized bf16 embeddings
// [OFF_PP)   : part_ps [NSL][BSZ] float (1 MiB) row j vs 64-col-tile s
// [OFF_PN)   : part_nm [NSL][BSZ] uint  (1 MiB) (float bits; dist>=0)
// [OFF_ACC)  : float total; int nv; int counter2
#define OFF_PP  (BSZ * DIM * 2)
#define OFF_PN  (OFF_PP + NSL * BSZ * 4)
#define OFF_ACC (OFF_PN + NSL * BSZ * 4)

__device__ __forceinline__ u16 f2bf_rne(float f) {
    unsigned x = __float_as_uint(f);
    x += 0x7FFFu + ((x >> 16) & 1u);
    return (u16)(x >> 16);
}

// async global->LDS, 16 B/lane; LDS dest = wave-uniform base + lane*16
__device__ __forceinline__ void gld_lds16(const u16* g, u16* l) {
    __builtin_amdgcn_global_load_lds(
        (const __attribute__((address_space(1))) unsigned int*)g,
        (__attribute__((address_space(3))) unsigned int*)l, 16, 0, 0);
}

// 4 waves/block, one row/wave: L2-normalize, cast bf16; init scalar accums.
__global__ __launch_bounds__(256) void ht_normalize(
        const float* __restrict__ emb, u16* __restrict__ ebf,
        float* __restrict__ acc_total, int* __restrict__ acc_nv,
        int* __restrict__ counter2) {
    const int lane = threadIdx.x & 63;
    const int row = blockIdx.x * 4 + (threadIdx.x >> 6);
    const float4* r4 = (const float4*)(emb + (size_t)row * DIM);
    float4 v0 = r4[lane * 2];
    float4 v1 = r4[lane * 2 + 1];
    float s = v0.x * v0.x + v0.y * v0.y + v0.z * v0.z + v0.w * v0.w
            + v1.x * v1.x + v1.y * v1.y + v1.z * v1.z + v1.w * v1.w;
#pragma unroll
    for (int off = 1; off < 64; off <<= 1) s += __shfl_xor(s, off);
    const float inv = 1.0f / fmaxf(sqrtf(s), 1e-12f);

    uint4 o;
    o.x = (unsigned)f2bf_rne(v0.x * inv) | ((unsigned)f2bf_rne(v0.y * inv) << 16);
    o.y = (unsigned)f2bf_rne(v0.z * inv) | ((unsigned)f2bf_rne(v0.w * inv) << 16);
    o.z = (unsigned)f2bf_rne(v1.x * inv) | ((unsigned)f2bf_rne(v1.y * inv) << 16);
    o.w = (unsigned)f2bf_rne(v1.z * inv) | ((unsigned)f2bf_rne(v1.w * inv) << 16);
    ((uint4*)(ebf + (size_t)row * DIM))[lane] = o;

    if (blockIdx.x == 0 && threadIdx.x == 0) {
        *acc_total = 0.0f; *acc_nv = 0; *counter2 = 0;
    }
}

// 128x128 tile per block, 4 waves 2x2, each wave 64x64 via 4x4
// mfma_f32_16x16x32_bf16. gld(16B) -> double-buffered [128][32] LDS with
// XOR-SWIZZLED granules: LDS slot (row,pos) holds global granule
// pos^((row>>1)&3) -- realized by swizzling each lane's GLOBAL source addr
// (stays inside the row's 64B line -> coalescing unchanged; gld fill order
// base+lane*16 untouched). Fragment read position = quad^((l15>>1)&3):
// bank = 16*(l15&1) + 4*(quad^((l15>>1)&3)) -> only l15/l15+8 alias = 2-way
// = free (m136). R7's unswizzled layout was 4-lane aliased (2.1M conflicts).
// Epilogue: part[2*bx+(wc>>6)][gi] has exactly ONE writer -> plain stores.
__global__ __launch_bounds__(256) void ht_gemm_reduce(
        const u16* __restrict__ ebf, const int* __restrict__ labels,
        float* __restrict__ part_ps, unsigned* __restrict__ part_nm) {
    __shared__ u16 sA[2][128 * 32];
    __shared__ u16 sB[2][128 * 32];
    __shared__ int sLI[128];
    __shared__ int sLJ[128];

    const int t = threadIdx.x;
    const int by = blockIdx.x >> 5;
    const int bx = blockIdx.x & 31;
    const int row0 = by * 128;
    const int col0 = bx * 128;

    if (t < 128) sLI[t] = labels[row0 + t];
    else         sLJ[t - 128] = labels[col0 + t - 128];

    const int lane = t & 63;
    const int wave = t >> 6;
    const int wr = (wave >> 1) * 64;
    const int wc = (wave & 1) * 64;
    const int l15 = lane & 15;
    const int quad = lane >> 4;

    // staging segments s0=t, s1=256+t; row=s>>2, LDS pos=s&3;
    // global source granule = (s&3) ^ ((row>>1)&3) = (s&3)^((s>>3)&3)
    const int s0 = t, s1 = 256 + t;
    const int gr0 = (s0 & 3) ^ ((s0 >> 3) & 3);
    const int gr1 = (s1 & 3) ^ ((s1 >> 3) & 3);
    const u16* gA0 = ebf + (size_t)(row0 + (s0 >> 2)) * DIM + gr0 * 8;
    const u16* gA1 = ebf + (size_t)(row0 + (s1 >> 2)) * DIM + gr1 * 8;
    const u16* gB0 = ebf + (size_t)(col0 + (s0 >> 2)) * DIM + gr0 * 8;
    const u16* gB1 = ebf + (size_t)(col0 + (s1 >> 2)) * DIM + gr1 * 8;
    const int lb0 = wave * 64 * 8;          // u16 offset of wave's 1KB chunk
    const int lb1 = (256 + wave * 64) * 8;

    // fragment read position (u16 offset within row): quad^((l15>>1)&3)
    const int qsw = (quad ^ ((l15 >> 1) & 3)) * 8;

    floatx4 acc[4][4] = {};

    // prologue: stage k=0 into buf 0
    gld_lds16(gA0, &sA[0][lb0]);
    gld_lds16(gA1, &sA[0][lb1]);
    gld_lds16(gB0, &sB[0][lb0]);
    gld_lds16(gB1, &sB[0][lb1]);

    int cur = 0;
    for (int ks = 0; ks < DIM / 32; ++ks) {
        __syncthreads();  // vmcnt drained: buf[cur] ready; buf[cur^1] reads done
        if (ks + 1 < DIM / 32) {
            const int kb = (ks + 1) * 32;
            gld_lds16(gA0 + kb, &sA[cur ^ 1][lb0]);
            gld_lds16(gA1 + kb, &sA[cur ^ 1][lb1]);
            gld_lds16(gB0 + kb, &sB[cur ^ 1][lb0]);
            gld_lds16(gB1 + kb, &sB[cur ^ 1][lb1]);
        }
        short8 af[4], bf[4];
#pragma unroll
        for (int mi = 0; mi < 4; ++mi)
            af[mi] = *(const short8*)(&sA[cur][(wr + mi * 16 + l15) * 32 + qsw]);
#pragma unroll
        for (int ni = 0; ni < 4; ++ni)
            bf[ni] = *(const short8*)(&sB[cur][(wc + ni * 16 + l15) * 32 + qsw]);
#pragma unroll
        for (int mi = 0; mi < 4; ++mi)
#pragma unroll
            for (int ni = 0; ni < 4; ++ni)
                acc[mi][ni] = __builtin_amdgcn_mfma_f32_16x16x32_bf16(
                    af[mi], bf[ni], acc[mi][ni], 0, 0, 0);
        cur ^= 1;
    }

    // epilogue: C/D layout col=l15, row=quad*4+reg (m89/m91 verified)
    const float INF = __uint_as_float(0x7F800000u);
    const int rslice = 2 * bx + (wc >> 6);
#pragma unroll
    for (int mi = 0; mi < 4; ++mi) {
        const int rbase = wr + mi * 16 + quad * 4;
#pragma unroll
        for (int r = 0; r < 4; ++r) {
            const int rloc = rbase + r;
            const int gi = row0 + rloc;
            const int rl = sLI[rloc];
            float ps = 0.0f, nm = INF;
#pragma unroll
            for (int ni = 0; ni < 4; ++ni) {
                const int cloc = wc + ni * 16 + l15;
                const int gj = col0 + cloc;
                const int cl = sLJ[cloc];
                const float d = __builtin_amdgcn_sqrtf(
                    fmaxf(2.0f - 2.0f * acc[mi][ni][r], 0.0f));
                if (rl == cl) { if (gi != gj) ps += d; }
                else          { nm = fminf(nm, d); }
            }
#pragma unroll
            for (int off = 1; off < 16; off <<= 1) {
                ps += __shfl_xor(ps, off);
                nm = fminf(nm, __shfl_xor(nm, off));
            }
            if (l15 == 0) {                 // sole writer of (rslice, gi)
                part_ps[rslice * BSZ + gi] = ps;
                part_nm[rslice * BSZ + gi] = __float_as_uint(nm);
            }
        }
    }
}

// 16 blocks x 256 threads: one row per thread. Reduce 64 slices (coalesced),
// per-block loss partials -> 2 device atomics per block; last block writes out.
__global__ __launch_bounds__(256) void ht_finalize(
        const float* __restrict__ part_ps, const unsigned* __restrict__ part_nm,
        const int* __restrict__ labels, float* __restrict__ acc_total,
        int* __restrict__ acc_nv, int* __restrict__ counter2,
        float* __restrict__ out) {
    __shared__ int hist[NCLS];
    __shared__ float sT[4];
    __shared__ int sN[4];
    const int t = threadIdx.x;
    if (t < NCLS) hist[t] = 0;
    __syncthreads();
    for (int i = t; i < BSZ; i += 256) atomicAdd(&hist[labels[i]], 1);
    __syncthreads();

    const int j = blockIdx.x * 256 + t;
    float ps = 0.0f;
    float nm = __uint_as_float(0x7F800000u);
#pragma unroll 8
    for (int s = 0; s < NSL; ++s) {
        ps += part_ps[s * BSZ + j];
        nm = fminf(nm, __uint_as_float(part_nm[s * BSZ + j]));
    }
    const int cnt = hist[labels[j]];
    const int pc = cnt - 1;
    const int nc = BSZ - cnt;
    float loss = 0.0f;
    int lv = 0;
    if (pc > 0 && nc > 0) {
        loss = fmaxf(ps / (float)pc - nm + MARGIN_F, 0.0f);
        lv = 1;
    }
#pragma unroll
    for (int off = 1; off < 64; off <<= 1) {
        loss += __shfl_xor(loss, off);
        lv += __shfl_xor(lv, off);
    }
    if ((t & 63) == 0) { sT[t >> 6] = loss; sN[t >> 6] = lv; }
    __syncthreads();
    if (t == 0) {
        const float tt = sT[0] + sT[1] + sT[2] + sT[3];
        const int nn = sN[0] + sN[1] + sN[2] + sN[3];
        __hip_atomic_fetch_add(acc_total, tt, __ATOMIC_ACQ_REL,
                               __HIP_MEMORY_SCOPE_AGENT);
        __hip_atomic_fetch_add(acc_nv, nn, __ATOMIC_ACQ_REL,
                               __HIP_MEMORY_SCOPE_AGENT);
        const int old2 = __hip_atomic_fetch_add(counter2, 1, __ATOMIC_ACQ_REL,
                                                __HIP_MEMORY_SCOPE_AGENT);
        if (old2 == NFIN - 1) {
            const float ft = __hip_atomic_load(acc_total, __ATOMIC_ACQUIRE,
                                               __HIP_MEMORY_SCOPE_AGENT);
            const int fn = __hip_atomic_load(acc_nv, __ATOMIC_ACQUIRE,
                                             __HIP_MEMORY_SCOPE_AGENT);
            out[0] = (fn > 0) ? ft / (float)fn : 0.0f;
        }
    }
}

extern "C" void kernel_launch(void* const* d_in, const int* in_sizes, int n_in,
                              void* d_out, int out_size, void* d_ws, size_t ws_size,
                              hipStream_t stream) {
    const float* emb = (const float*)d_in[0];
    const int* labels = (const int*)d_in[1];
    float* out = (float*)d_out;
    char* ws = (char*)d_ws;

    u16* ebf = (u16*)ws;
    float* part_ps = (float*)(ws + OFF_PP);
    unsigned* part_nm = (unsigned*)(ws + OFF_PN);
    float* acc_total = (float*)(ws + OFF_ACC);
    int* acc_nv = (int*)(ws + OFF_ACC + 4);
    int* counter2 = (int*)(ws + OFF_ACC + 8);

    ht_normalize<<<BSZ / 4, 256, 0, stream>>>(emb, ebf, acc_total, acc_nv,
                                              counter2);
    ht_gemm_reduce<<<NBLK, 256, 0, stream>>>(ebf, labels, part_ps, part_nm);
    ht_finalize<<<NFIN, 256, 0, stream>>>(part_ps, part_nm, labels,
                                          acc_total, acc_nv, counter2, out);
}

// Round 9
// 95.767 us; speedup vs baseline: 2.1056x; 1.0992x over previous
//
#include <hip/hip_runtime.h>
#include <hip/hip_bf16.h>

#define BSZ 4096
#define DIM 512
#define NCLS 64
#define MARGIN_F 1.0f
#define NT 32                      // 128-tiles per dim
#define NPAIR (NT * (NT + 1) / 2)  // 528 upper-tri pair tiles (by <= bx)
#define NSL (2 * NT)               // 64-column slices
#define NFIN 16                    // finalize blocks (16*256 = 4096 rows)

typedef short short8 __attribute__((ext_vector_type(8)));
typedef float floatx4 __attribute__((ext_vector_type(4)));
typedef unsigned short u16;

// ---------------- workspace layout ----------------
// [0)        : ebf16 BSZ*DIM u16 (4 MiB) normalized bf16 embeddings
// [OFF_PP)   : part_ps [NSL][BSZ] float (1 MiB) row j vs 64-col group s
// [OFF_PN)   : part_nm [NSL][BSZ] uint  (1 MiB) (float bits; dist>=0)
// [OFF_ACC)  : float total; int nv; int counter2
#define OFF_PP  (BSZ * DIM * 2)
#define OFF_PN  (OFF_PP + NSL * BSZ * 4)
#define OFF_ACC (OFF_PN + NSL * BSZ * 4)

__device__ __forceinline__ u16 f2bf_rne(float f) {
    unsigned x = __float_as_uint(f);
    x += 0x7FFFu + ((x >> 16) & 1u);
    return (u16)(x >> 16);
}

// async global->LDS, 16 B/lane; LDS dest = wave-uniform base + lane*16
__device__ __forceinline__ void gld_lds16(const u16* g, u16* l) {
    __builtin_amdgcn_global_load_lds(
        (const __attribute__((address_space(1))) unsigned int*)g,
        (__attribute__((address_space(3))) unsigned int*)l, 16, 0, 0);
}

// 4 waves/block, one row/wave: L2-normalize, cast bf16; init scalar accums.
__global__ __launch_bounds__(256) void ht_normalize(
        const float* __restrict__ emb, u16* __restrict__ ebf,
        float* __restrict__ acc_total, int* __restrict__ acc_nv,
        int* __restrict__ counter2) {
    const int lane = threadIdx.x & 63;
    const int row = blockIdx.x * 4 + (threadIdx.x >> 6);
    const float4* r4 = (const float4*)(emb + (size_t)row * DIM);
    float4 v0 = r4[lane * 2];
    float4 v1 = r4[lane * 2 + 1];
    float s = v0.x * v0.x + v0.y * v0.y + v0.z * v0.z + v0.w * v0.w
            + v1.x * v1.x + v1.y * v1.y + v1.z * v1.z + v1.w * v1.w;
#pragma unroll
    for (int off = 1; off < 64; off <<= 1) s += __shfl_xor(s, off);
    const float inv = 1.0f / fmaxf(sqrtf(s), 1e-12f);

    uint4 o;
    o.x = (unsigned)f2bf_rne(v0.x * inv) | ((unsigned)f2bf_rne(v0.y * inv) << 16);
    o.y = (unsigned)f2bf_rne(v0.z * inv) | ((unsigned)f2bf_rne(v0.w * inv) << 16);
    o.z = (unsigned)f2bf_rne(v1.x * inv) | ((unsigned)f2bf_rne(v1.y * inv) << 16);
    o.w = (unsigned)f2bf_rne(v1.z * inv) | ((unsigned)f2bf_rne(v1.w * inv) << 16);
    ((uint4*)(ebf + (size_t)row * DIM))[lane] = o;

    if (blockIdx.x == 0 && threadIdx.x == 0) {
        *acc_total = 0.0f; *acc_nv = 0; *counter2 = 0;
    }
}

// Upper-triangular 128x128 tiles (by <= bx): 2x less MFMA/staging work.
// K-loop identical to R8 (gld 16B, xor-swizzled granules, dbuf, 1 barrier).
// Epilogue, all plain stores, each part[s][j] written EXACTLY once:
//   row path: slice 2*bx+(wc>>6), rows gi of by-tile  (one wave per entry)
//   col path (off-diag only): cross-quad reduce -> slice 2*by+(wr>>6),
//            cols gj of bx-tile (one wave per entry)
//   diag blocks: row path alone covers the tile; col path skipped.
__global__ __launch_bounds__(256) void ht_gemm_reduce(
        const u16* __restrict__ ebf, const int* __restrict__ labels,
        float* __restrict__ part_ps, unsigned* __restrict__ part_nm) {
    __shared__ u16 sA[2][128 * 32];
    __shared__ u16 sB[2][128 * 32];
    __shared__ int sLI[128];
    __shared__ int sLJ[128];

    // decode linear block id -> upper-tri (by, bx), by <= bx
    int rem = blockIdx.x, by = 0;
    while (rem >= NT - by) { rem -= NT - by; ++by; }
    const int bx = by + rem;
    const bool offd = (bx != by);

    const int t = threadIdx.x;
    const int row0 = by * 128;
    const int col0 = bx * 128;

    if (t < 128) sLI[t] = labels[row0 + t];
    else         sLJ[t - 128] = labels[col0 + t - 128];

    const int lane = t & 63;
    const int wave = t >> 6;
    const int wr = (wave >> 1) * 64;
    const int wc = (wave & 1) * 64;
    const int l15 = lane & 15;
    const int quad = lane >> 4;

    // staging segments s0=t, s1=256+t; row=s>>2, LDS pos=s&3;
    // global source granule xor-swizzled: (s&3)^((s>>3)&3)
    const int s0 = t, s1 = 256 + t;
    const int gr0 = (s0 & 3) ^ ((s0 >> 3) & 3);
    const int gr1 = (s1 & 3) ^ ((s1 >> 3) & 3);
    const u16* gA0 = ebf + (size_t)(row0 + (s0 >> 2)) * DIM + gr0 * 8;
    const u16* gA1 = ebf + (size_t)(row0 + (s1 >> 2)) * DIM + gr1 * 8;
    const u16* gB0 = ebf + (size_t)(col0 + (s0 >> 2)) * DIM + gr0 * 8;
    const u16* gB1 = ebf + (size_t)(col0 + (s1 >> 2)) * DIM + gr1 * 8;
    const int lb0 = wave * 64 * 8;          // u16 offset of wave's 1KB chunk
    const int lb1 = (256 + wave * 64) * 8;

    // fragment read position: quad^((l15>>1)&3) -> max 2-way bank alias
    const int qsw = (quad ^ ((l15 >> 1) & 3)) * 8;

    floatx4 acc[4][4] = {};

    gld_lds16(gA0, &sA[0][lb0]);
    gld_lds16(gA1, &sA[0][lb1]);
    gld_lds16(gB0, &sB[0][lb0]);
    gld_lds16(gB1, &sB[0][lb1]);

    int cur = 0;
    for (int ks = 0; ks < DIM / 32; ++ks) {
        __syncthreads();  // vmcnt drained: buf[cur] ready; buf[cur^1] reads done
        if (ks + 1 < DIM / 32) {
            const int kb = (ks + 1) * 32;
            gld_lds16(gA0 + kb, &sA[cur ^ 1][lb0]);
            gld_lds16(gA1 + kb, &sA[cur ^ 1][lb1]);
            gld_lds16(gB0 + kb, &sB[cur ^ 1][lb0]);
            gld_lds16(gB1 + kb, &sB[cur ^ 1][lb1]);
        }
        short8 af[4], bf[4];
#pragma unroll
        for (int mi = 0; mi < 4; ++mi)
            af[mi] = *(const short8*)(&sA[cur][(wr + mi * 16 + l15) * 32 + qsw]);
#pragma unroll
        for (int ni = 0; ni < 4; ++ni)
            bf[ni] = *(const short8*)(&sB[cur][(wc + ni * 16 + l15) * 32 + qsw]);
#pragma unroll
        for (int mi = 0; mi < 4; ++mi)
#pragma unroll
            for (int ni = 0; ni < 4; ++ni)
                acc[mi][ni] = __builtin_amdgcn_mfma_f32_16x16x32_bf16(
                    af[mi], bf[ni], acc[mi][ni], 0, 0, 0);
        cur ^= 1;
    }

    // epilogue: C/D layout col=l15, row=quad*4+reg (m89/m91 verified)
    const float INF = __uint_as_float(0x7F800000u);
    const int rslice = 2 * bx + (wc >> 6);
    float psc[4] = {0.f, 0.f, 0.f, 0.f};
    float nmc[4] = {INF, INF, INF, INF};
#pragma unroll
    for (int mi = 0; mi < 4; ++mi) {
        const int rbase = wr + mi * 16 + quad * 4;
#pragma unroll
        for (int r = 0; r < 4; ++r) {
            const int rloc = rbase + r;
            const int gi = row0 + rloc;
            const int rl = sLI[rloc];
            float ps = 0.0f, nm = INF;
#pragma unroll
            for (int ni = 0; ni < 4; ++ni) {
                const int cloc = wc + ni * 16 + l15;
                const int gj = col0 + cloc;
                const int cl = sLJ[cloc];
                const float d = __builtin_amdgcn_sqrtf(
                    fmaxf(2.0f - 2.0f * acc[mi][ni][r], 0.0f));
                if (rl == cl) {
                    if (gi != gj) ps += d;      // drop self-pair (diag only)
                    if (offd) psc[ni] += d;
                } else {
                    nm = fminf(nm, d);
                    if (offd) nmc[ni] = fminf(nmc[ni], d);
                }
            }
#pragma unroll
            for (int off = 1; off < 16; off <<= 1) {
                ps += __shfl_xor(ps, off);
                nm = fminf(nm, __shfl_xor(nm, off));
            }
            if (l15 == 0) {                 // sole writer of (rslice, gi)
                part_ps[rslice * BSZ + gi] = ps;
                part_nm[rslice * BSZ + gi] = __float_as_uint(nm);
            }
        }
    }
    if (offd) {
        // col stats: wave (wr,wc) is the SOLE writer of
        // part[2*by+(wr>>6)][col0+wc+ni*16+l15] -> plain stores.
        const int cslice = 2 * by + (wr >> 6);
#pragma unroll
        for (int ni = 0; ni < 4; ++ni) {
            float ps = psc[ni], nm = nmc[ni];
            ps += __shfl_xor(ps, 16); ps += __shfl_xor(ps, 32);
            nm = fminf(nm, __shfl_xor(nm, 16));
            nm = fminf(nm, __shfl_xor(nm, 32));
            if (quad == 0) {
                const int gj = col0 + wc + ni * 16 + l15;
                part_ps[cslice * BSZ + gj] = ps;
                part_nm[cslice * BSZ + gj] = __float_as_uint(nm);
            }
        }
    }
}

// 16 blocks x 256 threads: one row per thread. Reduce 64 slices (coalesced),
// per-block loss partials -> 2 device atomics per block; last block writes out.
__global__ __launch_bounds__(256) void ht_finalize(
        const float* __restrict__ part_ps, const unsigned* __restrict__ part_nm,
        const int* __restrict__ labels, float* __restrict__ acc_total,
        int* __restrict__ acc_nv, int* __restrict__ counter2,
        float* __restrict__ out) {
    __shared__ int hist[NCLS];
    __shared__ float sT[4];
    __shared__ int sN[4];
    const int t = threadIdx.x;
    if (t < NCLS) hist[t] = 0;
    __syncthreads();
    for (int i = t; i < BSZ; i += 256) atomicAdd(&hist[labels[i]], 1);
    __syncthreads();

    const int j = blockIdx.x * 256 + t;
    float ps = 0.0f;
    float nm = __uint_as_float(0x7F800000u);
#pragma unroll 8
    for (int s = 0; s < NSL; ++s) {
        ps += part_ps[s * BSZ + j];
        nm = fminf(nm, __uint_as_float(part_nm[s * BSZ + j]));
    }
    const int cnt = hist[labels[j]];
    const int pc = cnt - 1;
    const int nc = BSZ - cnt;
    float loss = 0.0f;
    int lv = 0;
    if (pc > 0 && nc > 0) {
        loss = fmaxf(ps / (float)pc - nm + MARGIN_F, 0.0f);
        lv = 1;
    }
#pragma unroll
    for (int off = 1; off < 64; off <<= 1) {
        loss += __shfl_xor(loss, off);
        lv += __shfl_xor(lv, off);
    }
    if ((t & 63) == 0) { sT[t >> 6] = loss; sN[t >> 6] = lv; }
    __syncthreads();
    if (t == 0) {
        const float tt = sT[0] + sT[1] + sT[2] + sT[3];
        const int nn = sN[0] + sN[1] + sN[2] + sN[3];
        __hip_atomic_fetch_add(acc_total, tt, __ATOMIC_ACQ_REL,
                               __HIP_MEMORY_SCOPE_AGENT);
        __hip_atomic_fetch_add(acc_nv, nn, __ATOMIC_ACQ_REL,
                               __HIP_MEMORY_SCOPE_AGENT);
        const int old2 = __hip_atomic_fetch_add(counter2, 1, __ATOMIC_ACQ_REL,
                                                __HIP_MEMORY_SCOPE_AGENT);
        if (old2 == NFIN - 1) {
            const float ft = __hip_atomic_load(acc_total, __ATOMIC_ACQUIRE,
                                               __HIP_MEMORY_SCOPE_AGENT);
            const int fn = __hip_atomic_load(acc_nv, __ATOMIC_ACQUIRE,
                                             __HIP_MEMORY_SCOPE_AGENT);
            out[0] = (fn > 0) ? ft / (float)fn : 0.0f;
        }
    }
}

extern "C" void kernel_launch(void* const* d_in, const int* in_sizes, int n_in,
                              void* d_out, int out_size, void* d_ws, size_t ws_size,
                              hipStream_t stream) {
    const float* emb = (const float*)d_in[0];
    const int* labels = (const int*)d_in[1];
    float* out = (float*)d_out;
    char* ws = (char*)d_ws;

    u16* ebf = (u16*)ws;
    float* part_ps = (float*)(ws + OFF_PP);
    unsigned* part_nm = (unsigned*)(ws + OFF_PN);
    float* acc_total = (float*)(ws + OFF_ACC);
    int* acc_nv = (int*)(ws + OFF_ACC + 4);
    int* counter2 = (int*)(ws + OFF_ACC + 8);

    ht_normalize<<<BSZ / 4, 256, 0, stream>>>(emb, ebf, acc_total, acc_nv,
                                              counter2);
    ht_gemm_reduce<<<NPAIR, 256, 0, stream>>>(ebf, labels, part_ps, part_nm);
    ht_finalize<<<NFIN, 256, 0, stream>>>(part_ps, part_nm, labels,
                                          acc_total, acc_nv, counter2, out);
}